// Round 10
// baseline (1836.844 us; speedup 1.0000x reference)
//
#include <hip/hip_runtime.h>
#include <stdint.h>
#include <stddef.h>

#define T_ 512
#define B_ 128
#define D_ 256
#define H_ 256
#define NR 768               // 3*H
#define OUT_MAIN 33554432ull // B*T*2H
#define XT_STRIDE 12288      // u16 per (wg, t): 512 threads * 24 values
#define HB 280               // hbuf row stride in u16

typedef __attribute__((ext_vector_type(4))) float f32x4;
typedef __attribute__((ext_vector_type(8))) short s16x8;
typedef __attribute__((ext_vector_type(4))) uint32_t u32x4;
typedef __attribute__((ext_vector_type(2))) uint32_t u32x2;

__device__ __forceinline__ unsigned short f2bf(float f) {
    union { float f; uint32_t u; } v; v.f = f;
    return (unsigned short)((v.u + 0x7FFFu + ((v.u >> 16) & 1u)) >> 16);
}
__device__ __forceinline__ float bf2f(unsigned short h) {
    union { uint32_t u; float f; } v; v.u = ((uint32_t)h) << 16;
    return v.f;
}
__device__ __forceinline__ uint32_t cvtpk(float a, float b) {
    uint32_t r;
    asm("v_cvt_pk_bf16_f32 %0, %1, %2" : "=v"(r) : "v"(a), "v"(b));
    return r;
}
__device__ __forceinline__ float sigm(float x) {
    return __builtin_amdgcn_rcpf(1.f + __expf(-x));
}
__device__ __forceinline__ float tanh_(float x) {
    float e = __expf(2.f * x);
    return 1.f - 2.f * __builtin_amdgcn_rcpf(e + 1.f);
}
__device__ __forceinline__ s16x8 pack8(const float* f) {
    union { s16x8 v; unsigned short u[8]; } p;
#pragma unroll
    for (int i = 0; i < 8; ++i) p.u[i] = f2bf(f[i]);
    return p.v;
}

// ---------------- kernel 0: convert w_ih (fw|bw) to bf16 ----------------
__global__ void k_convert(const float* __restrict__ wf, const float* __restrict__ wb,
                          unsigned short* __restrict__ dst) {
    int i = blockIdx.x * blockDim.x + threadIdx.x;
    const int n = NR * D_;
    if (i < n) dst[i] = f2bf(wf[i]);
    else if (i < 2 * n) dst[i] = f2bf(wb[i - n]);
}

// ---------------- kernel 1: XT = x @ w_ih^T + bias; both dirs per block ----------
// grid (T_, 4): y = q2 (rows q2*32..+32). One A-staging pass feeds both dirs' 768 cols.
__global__ __launch_bounds__(512, 2) void k_xgemm(
    const float* __restrict__ x, const unsigned short* __restrict__ wbf,
    const float* __restrict__ bih_f, const float* __restrict__ bhh_f,
    const float* __restrict__ bih_b, const float* __restrict__ bhh_b,
    unsigned short* __restrict__ XT)
{
    __shared__ __align__(16) unsigned short lds_a[32 * 72];
    __shared__ __align__(16) unsigned short xt_l[2 * XT_STRIDE];
    const int tid = threadIdx.x, lane = tid & 63, wn = tid >> 6;
    const int t = blockIdx.x;
    const int q2 = blockIdx.y;

    f32x4 acc[2][2][6]; // [dir][mt][nt]
#pragma unroll
    for (int d = 0; d < 2; ++d)
#pragma unroll
        for (int m = 0; m < 2; ++m)
#pragma unroll
            for (int n = 0; n < 6; ++n) acc[d][m][n] = (f32x4){0.f, 0.f, 0.f, 0.f};

    for (int kb = 0; kb < 4; ++kb) {
        if (kb) __syncthreads();
        {   // stage A tile (32 rows x 64 k) fp32 -> bf16 (once; dir-invariant)
            int row = tid >> 4, c4 = (tid & 15) * 4;
            const float* src = x + ((size_t)(q2 * 32 + row) * T_ + t) * D_ + kb * 64 + c4;
            f32x4 f = *(const f32x4*)src;
            u32x2 p = { cvtpk(f[0], f[1]), cvtpk(f[2], f[3]) };
            *(u32x2*)&lds_a[row * 72 + c4] = p;
        }
        __syncthreads();
#pragma unroll
        for (int kt = 0; kt < 2; ++kt) {
            s16x8 av[2];
#pragma unroll
            for (int mt = 0; mt < 2; ++mt) {
                int r = mt * 16 + (lane & 15);
                av[mt] = *(const s16x8*)&lds_a[r * 72 + kt * 32 + (lane >> 4) * 8];
            }
#pragma unroll
            for (int d = 0; d < 2; ++d) {
#pragma unroll
                for (int nt = 0; nt < 6; ++nt) {
                    int c = d * NR + wn * 96 + nt * 16 + (lane & 15);
                    s16x8 bv = *(const s16x8*)(wbf + (size_t)c * D_ + kb * 64 + kt * 32 + (lane >> 4) * 8);
#pragma unroll
                    for (int mt = 0; mt < 2; ++mt)
                        acc[d][mt][nt] = __builtin_amdgcn_mfma_f32_16x16x32_bf16(av[mt], bv, acc[d][mt][nt], 0, 0, 0);
                }
            }
        }
    }
    // epilogue per dir: bias + transpose to recur layout in LDS, coalesced store
#pragma unroll 1
    for (int d = 0; d < 2; ++d) {
        const float* bih = d ? bih_b : bih_f;
        const float* bhh = d ? bhh_b : bhh_f;
        __syncthreads();
#pragma unroll
        for (int nt = 0; nt < 6; ++nt) {
            const int cw = wn * 96 + nt * 16 + (lane & 15);
            const int gate = cw >> 8, j = cw & 255;
            const int jt = (j >> 4) & 1;
            const int rtid = (j >> 5) * 64 + ((lane >> 4) << 4) + (j & 15);
            float bias = bih[cw] + (cw < 512 ? bhh[cw] : 0.f);
#pragma unroll
            for (int mt = 0; mt < 2; ++mt) {
#pragma unroll
                for (int q = 0; q < 4; ++q) {
                    int v = (jt * 4 + q) * 3 + gate;
                    xt_l[mt * XT_STRIDE + rtid * 24 + v] = f2bf(acc[d][mt][nt][q] + bias);
                }
            }
        }
        __syncthreads();
#pragma unroll
        for (int half = 0; half < 2; ++half) {
            size_t base = ((size_t)(d * 8 + q2 * 2 + half) * T_ + t) * XT_STRIDE;
#pragma unroll
            for (int k = 0; k < 3; ++k)
                *(u32x4*)(XT + base + (size_t)tid * 24 + k * 8)
                    = *(const u32x4*)&xt_l[half * XT_STRIDE + tid * 24 + k * 8];
        }
    }
}

// ---------------- kernel 2: recurrence (round-8 version, verbatim) ----------------
template<int P>
__device__ __forceinline__ void gru_step(
    int s, int dir, int b0, int tid, int lane, int wid,
    const unsigned short* __restrict__ XTw, float* __restrict__ out,
    unsigned short* hb, const s16x8 (&fB)[6][8], float bhn0, float bhn1,
    s16x8 (&CUR)[3], s16x8 (&NXT)[3])
{
    const int t  = dir ? (T_ - 1 - s) : s;
    const int sn = (s < T_ - 1) ? s + 1 : s;
    const int tn = dir ? (T_ - 1 - sn) : sn;
    {   // prefetch xT(t+1) into registers (3 x dwordx4), consumed next step
        const s16x8* p = (const s16x8*)(XTw + (size_t)tn * XT_STRIDE) + (size_t)tid * 3;
        NXT[0] = p[0]; NXT[1] = p[1]; NXT[2] = p[2];
    }
    const unsigned short* hr = hb + P * (16 * HB);
    unsigned short*       hw = hb + (P ^ 1) * (16 * HB);

    f32x4 acc[6];
#pragma unroll
    for (int n = 0; n < 6; ++n) acc[n] = (f32x4){0.f, 0.f, 0.f, 0.f};
#pragma unroll
    for (int k0 = 0; k0 < 8; ++k0) {
        s16x8 a = *(const s16x8*)&hr[(lane & 15) * HB + k0 * 32 + (lane >> 4) * 8];
#pragma unroll
        for (int nt = 0; nt < 6; ++nt)
            acc[nt] = __builtin_amdgcn_mfma_f32_16x16x32_bf16(a, fB[nt][k0], acc[nt], 0, 0, 0);
    }
#pragma unroll
    for (int jt = 0; jt < 2; ++jt) {
        const int j = 32 * wid + jt * 16 + (lane & 15);
        const float bn = jt ? bhn1 : bhn0;
#pragma unroll
        for (int q = 0; q < 4; ++q) {
            const int row = (lane >> 4) * 4 + q;
            const int v = (jt * 4 + q) * 3;
            float xr = bf2f((unsigned short)CUR[(v + 0) >> 3][(v + 0) & 7]);
            float xz = bf2f((unsigned short)CUR[(v + 1) >> 3][(v + 1) & 7]);
            float xn = bf2f((unsigned short)CUR[(v + 2) >> 3][(v + 2) & 7]);
            float hv = bf2f(hr[row * HB + j]);
            float rg = sigm(acc[jt][q] + xr);
            float zg = sigm(acc[2 + jt][q] + xz);
            float ng = tanh_(xn + rg * (acc[4 + jt][q] + bn));
            float hnew = ng + zg * (hv - ng);
            hw[row * HB + j] = f2bf(hnew);
            size_t off = ((size_t)(b0 + row) << 18) + ((size_t)t << 9) + (size_t)dir * 256 + j;
            out[off] = hnew;
            if (s == T_ - 1)
                out[OUT_MAIN + (size_t)dir * B_ * H_ + (size_t)(b0 + row) * H_ + j] = hnew;
        }
    }
    __builtin_amdgcn_sched_barrier(0);
    asm volatile("s_waitcnt lgkmcnt(0)");
    __builtin_amdgcn_s_barrier();
    __builtin_amdgcn_sched_barrier(0);
}

__global__ __launch_bounds__(512, 2) void k_recur(
    const float* __restrict__ whh_f, const float* __restrict__ whh_b,
    const float* __restrict__ bhh_f, const float* __restrict__ bhh_b,
    const unsigned short* __restrict__ XT,
    float* __restrict__ out)
{
    __shared__ __align__(16) unsigned short hb[2 * 16 * HB];
    const int tid = threadIdx.x, lane = tid & 63, wid = tid >> 6;
    const int bid = blockIdx.x;
    const int dir = bid >> 3, b0 = (bid & 7) * 16;
    const float* whh = dir ? whh_b : whh_f;
    const float* bhh = dir ? bhh_b : bhh_f;

    // stationary w_hh fragments: 48 x s16x8 = 192 regs/lane
    s16x8 fB[6][8];
#pragma unroll
    for (int g = 0; g < 3; ++g) {
#pragma unroll
        for (int half = 0; half < 2; ++half) {
            int nt = 2 * g + half;
            int cb = g * 256 + 32 * wid + half * 16;
#pragma unroll
            for (int k0 = 0; k0 < 8; ++k0) {
                const float* sp = whh + (size_t)(cb + (lane & 15)) * H_ + k0 * 32 + (lane >> 4) * 8;
                float fv[8];
                *(f32x4*)&fv[0] = *(const f32x4*)(sp);
                *(f32x4*)&fv[4] = *(const f32x4*)(sp + 4);
                fB[nt][k0] = pack8(fv);
            }
        }
    }
    const float bhn0 = bhh[512 + 32 * wid + (lane & 15)];
    const float bhn1 = bhh[512 + 32 * wid + 16 + (lane & 15)];

    for (int i = tid; i < 16 * HB / 2; i += 512) ((uint32_t*)hb)[i] = 0;
    __syncthreads();

    const unsigned short* XTw = XT + (size_t)bid * T_ * XT_STRIDE;
    s16x8 XA[3], XB[3];
    {   // prologue: load xT(t(0))
        const int t0 = dir ? (T_ - 1) : 0;
        const s16x8* p = (const s16x8*)(XTw + (size_t)t0 * XT_STRIDE) + (size_t)tid * 3;
        XA[0] = p[0]; XA[1] = p[1]; XA[2] = p[2];
    }
#pragma unroll 1
    for (int s = 0; s < T_; s += 2) {
        gru_step<0>(s,     dir, b0, tid, lane, wid, XTw, out, hb, fB, bhn0, bhn1, XA, XB);
        gru_step<1>(s + 1, dir, b0, tid, lane, wid, XTw, out, hb, fB, bhn0, bhn1, XB, XA);
    }
}

extern "C" void kernel_launch(void* const* d_in, const int* in_sizes, int n_in,
                              void* d_out, int out_size, void* d_ws, size_t ws_size,
                              hipStream_t stream) {
    const float* x     = (const float*)d_in[0];
    const float* wih_f = (const float*)d_in[1];
    const float* whh_f = (const float*)d_in[2];
    const float* bih_f = (const float*)d_in[3];
    const float* bhh_f = (const float*)d_in[4];
    const float* wih_b = (const float*)d_in[5];
    const float* whh_b = (const float*)d_in[6];
    const float* bih_b = (const float*)d_in[7];
    const float* bhh_b = (const float*)d_in[8];
    float* out = (float*)d_out;

    unsigned short* wbf = (unsigned short*)d_ws;
    unsigned short* XT  = (unsigned short*)((char*)d_ws + 786432);

    k_convert<<<dim3(768), dim3(512), 0, stream>>>(wih_f, wih_b, wbf);
    k_xgemm<<<dim3(512, 4), dim3(512), 0, stream>>>(x, wbf, bih_f, bhh_f, bih_b, bhh_b, XT);
    k_recur<<<dim3(16), dim3(512), 0, stream>>>(whh_f, whh_b, bhh_f, bhh_b, XT, out);
}

// Round 11
// 1469.904 us; speedup vs baseline: 1.2496x; 1.2496x over previous
//
#include <hip/hip_runtime.h>
#include <stdint.h>
#include <stddef.h>

#define T_ 512
#define B_ 128
#define D_ 256
#define H_ 256
#define NR 768               // 3*H
#define OUT_MAIN 33554432ull // B*T*2H
#define XT_STRIDE 12288      // u16 per (wg, t): 512 threads * 24 values
#define HB 280               // hbuf row stride in u16

typedef __attribute__((ext_vector_type(4))) float f32x4;
typedef __attribute__((ext_vector_type(8))) short s16x8;
typedef __attribute__((ext_vector_type(4))) uint32_t u32x4;
typedef __attribute__((ext_vector_type(2))) uint32_t u32x2;

__device__ __forceinline__ unsigned short f2bf(float f) {
    union { float f; uint32_t u; } v; v.f = f;
    return (unsigned short)((v.u + 0x7FFFu + ((v.u >> 16) & 1u)) >> 16);
}
__device__ __forceinline__ float bf2f(unsigned short h) {
    union { uint32_t u; float f; } v; v.u = ((uint32_t)h) << 16;
    return v.f;
}
__device__ __forceinline__ uint32_t cvtpk(float a, float b) {
    uint32_t r;
    asm("v_cvt_pk_bf16_f32 %0, %1, %2" : "=v"(r) : "v"(a), "v"(b));
    return r;
}
__device__ __forceinline__ float sigm(float x) {
    return __builtin_amdgcn_rcpf(1.f + __expf(-x));
}
__device__ __forceinline__ float tanh_(float x) {
    float e = __expf(2.f * x);
    return 1.f - 2.f * __builtin_amdgcn_rcpf(e + 1.f);
}
__device__ __forceinline__ s16x8 pack8(const float* f) {
    union { s16x8 v; unsigned short u[8]; } p;
#pragma unroll
    for (int i = 0; i < 8; ++i) p.u[i] = f2bf(f[i]);
    return p.v;
}

// ---------------- kernel 0: convert w_ih (fw|bw) to bf16 ----------------
__global__ void k_convert(const float* __restrict__ wf, const float* __restrict__ wb,
                          unsigned short* __restrict__ dst) {
    int i = blockIdx.x * blockDim.x + threadIdx.x;
    const int n = NR * D_;
    if (i < n) dst[i] = f2bf(wf[i]);
    else if (i < 2 * n) dst[i] = f2bf(wb[i - n]);
}

// ---------------- kernel 1: XT = x @ w_ih^T + bias (round-4/8 version, verbatim) --
// grid (T_, 8): y = dir*4 + q2. Rows q2*32..+32 (M=32), N=768, K=256.
__global__ __launch_bounds__(512, 2) void k_xgemm(
    const float* __restrict__ x, const unsigned short* __restrict__ wbf,
    const float* __restrict__ bih_f, const float* __restrict__ bhh_f,
    const float* __restrict__ bih_b, const float* __restrict__ bhh_b,
    unsigned short* __restrict__ XT)
{
    __shared__ __align__(16) unsigned short lds_a[32 * 72];
    __shared__ __align__(16) unsigned short xt_l[2 * XT_STRIDE];
    const int tid = threadIdx.x, lane = tid & 63, wn = tid >> 6;
    const int t = blockIdx.x;
    const int dir = blockIdx.y >> 2, q2 = blockIdx.y & 3;

    f32x4 acc[2][6];
#pragma unroll
    for (int m = 0; m < 2; ++m)
#pragma unroll
        for (int n = 0; n < 6; ++n) acc[m][n] = (f32x4){0.f, 0.f, 0.f, 0.f};

    for (int kb = 0; kb < 4; ++kb) {
        if (kb) __syncthreads();
        {   // stage A tile (32 rows x 64 k) fp32 -> bf16
            int row = tid >> 4, c4 = (tid & 15) * 4;
            const float* src = x + ((size_t)(q2 * 32 + row) * T_ + t) * D_ + kb * 64 + c4;
            f32x4 f = *(const f32x4*)src;
            u32x2 p = { cvtpk(f[0], f[1]), cvtpk(f[2], f[3]) };
            *(u32x2*)&lds_a[row * 72 + c4] = p;
        }
        __syncthreads();
#pragma unroll
        for (int kt = 0; kt < 2; ++kt) {
            s16x8 av[2];
#pragma unroll
            for (int mt = 0; mt < 2; ++mt) {
                int r = mt * 16 + (lane & 15);
                av[mt] = *(const s16x8*)&lds_a[r * 72 + kt * 32 + (lane >> 4) * 8];
            }
#pragma unroll
            for (int nt = 0; nt < 6; ++nt) {
                int c = dir * NR + wn * 96 + nt * 16 + (lane & 15);
                s16x8 bv = *(const s16x8*)(wbf + (size_t)c * D_ + kb * 64 + kt * 32 + (lane >> 4) * 8);
#pragma unroll
                for (int mt = 0; mt < 2; ++mt)
                    acc[mt][nt] = __builtin_amdgcn_mfma_f32_16x16x32_bf16(av[mt], bv, acc[mt][nt], 0, 0, 0);
            }
        }
    }
    // epilogue: bias, transpose to recur layout in LDS
    const float* bih = dir ? bih_b : bih_f;
    const float* bhh = dir ? bhh_b : bhh_f;
    __syncthreads();
#pragma unroll
    for (int nt = 0; nt < 6; ++nt) {
        const int cw = wn * 96 + nt * 16 + (lane & 15);
        const int gate = cw >> 8, j = cw & 255;
        const int jt = (j >> 4) & 1;
        const int rtid = (j >> 5) * 64 + ((lane >> 4) << 4) + (j & 15);
        float bias = bih[cw] + (cw < 512 ? bhh[cw] : 0.f);
#pragma unroll
        for (int mt = 0; mt < 2; ++mt) {
#pragma unroll
            for (int q = 0; q < 4; ++q) {
                int v = (jt * 4 + q) * 3 + gate;
                xt_l[mt * XT_STRIDE + rtid * 24 + v] = f2bf(acc[mt][nt][q] + bias);
            }
        }
    }
    __syncthreads();
    // coalesced global write: per half-tile 24 KB contiguous
#pragma unroll
    for (int half = 0; half < 2; ++half) {
        size_t base = ((size_t)(dir * 8 + q2 * 2 + half) * T_ + t) * XT_STRIDE;
#pragma unroll
        for (int k = 0; k < 3; ++k)
            *(u32x4*)(XT + base + (size_t)tid * 24 + k * 8)
                = *(const u32x4*)&xt_l[half * XT_STRIDE + tid * 24 + k * 8];
    }
}

// ---------------- kernel 2: recurrence (round-2/8 version, verbatim) --------------
template<int P>
__device__ __forceinline__ void gru_step(
    int s, int dir, int b0, int tid, int lane, int wid,
    const unsigned short* __restrict__ XTw, float* __restrict__ out,
    unsigned short* hb, const s16x8 (&fB)[6][8], float bhn0, float bhn1,
    s16x8 (&CUR)[3], s16x8 (&NXT)[3])
{
    const int t  = dir ? (T_ - 1 - s) : s;
    const int sn = (s < T_ - 1) ? s + 1 : s;
    const int tn = dir ? (T_ - 1 - sn) : sn;
    {   // prefetch xT(t+1) into registers (3 x dwordx4), consumed next step
        const s16x8* p = (const s16x8*)(XTw + (size_t)tn * XT_STRIDE) + (size_t)tid * 3;
        NXT[0] = p[0]; NXT[1] = p[1]; NXT[2] = p[2];
    }
    const unsigned short* hr = hb + P * (16 * HB);
    unsigned short*       hw = hb + (P ^ 1) * (16 * HB);

    f32x4 acc[6];
#pragma unroll
    for (int n = 0; n < 6; ++n) acc[n] = (f32x4){0.f, 0.f, 0.f, 0.f};
#pragma unroll
    for (int k0 = 0; k0 < 8; ++k0) {
        s16x8 a = *(const s16x8*)&hr[(lane & 15) * HB + k0 * 32 + (lane >> 4) * 8];
#pragma unroll
        for (int nt = 0; nt < 6; ++nt)
            acc[nt] = __builtin_amdgcn_mfma_f32_16x16x32_bf16(a, fB[nt][k0], acc[nt], 0, 0, 0);
    }
#pragma unroll
    for (int jt = 0; jt < 2; ++jt) {
        const int j = 32 * wid + jt * 16 + (lane & 15);
        const float bn = jt ? bhn1 : bhn0;
#pragma unroll
        for (int q = 0; q < 4; ++q) {
            const int row = (lane >> 4) * 4 + q;
            const int v = (jt * 4 + q) * 3;
            float xr = bf2f((unsigned short)CUR[(v + 0) >> 3][(v + 0) & 7]);
            float xz = bf2f((unsigned short)CUR[(v + 1) >> 3][(v + 1) & 7]);
            float xn = bf2f((unsigned short)CUR[(v + 2) >> 3][(v + 2) & 7]);
            float hv = bf2f(hr[row * HB + j]);
            float rg = sigm(acc[jt][q] + xr);
            float zg = sigm(acc[2 + jt][q] + xz);
            float ng = tanh_(xn + rg * (acc[4 + jt][q] + bn));
            float hnew = ng + zg * (hv - ng);
            hw[row * HB + j] = f2bf(hnew);
            size_t off = ((size_t)(b0 + row) << 18) + ((size_t)t << 9) + (size_t)dir * 256 + j;
            out[off] = hnew;
            if (s == T_ - 1)
                out[OUT_MAIN + (size_t)dir * B_ * H_ + (size_t)(b0 + row) * H_ + j] = hnew;
        }
    }
    __builtin_amdgcn_sched_barrier(0);
    asm volatile("s_waitcnt lgkmcnt(0)");
    __builtin_amdgcn_s_barrier();
    __builtin_amdgcn_sched_barrier(0);
}

__global__ __launch_bounds__(512, 2) void k_recur(
    const float* __restrict__ whh_f, const float* __restrict__ whh_b,
    const float* __restrict__ bhh_f, const float* __restrict__ bhh_b,
    const unsigned short* __restrict__ XT,
    float* __restrict__ out)
{
    __shared__ __align__(16) unsigned short hb[2 * 16 * HB];
    const int tid = threadIdx.x, lane = tid & 63, wid = tid >> 6;
    const int bid = blockIdx.x;
    const int dir = bid >> 3, b0 = (bid & 7) * 16;
    const float* whh = dir ? whh_b : whh_f;
    const float* bhh = dir ? bhh_b : bhh_f;

    // stationary w_hh fragments: 48 x s16x8 = 192 regs/lane
    s16x8 fB[6][8];
#pragma unroll
    for (int g = 0; g < 3; ++g) {
#pragma unroll
        for (int half = 0; half < 2; ++half) {
            int nt = 2 * g + half;
            int cb = g * 256 + 32 * wid + half * 16;
#pragma unroll
            for (int k0 = 0; k0 < 8; ++k0) {
                const float* sp = whh + (size_t)(cb + (lane & 15)) * H_ + k0 * 32 + (lane >> 4) * 8;
                float fv[8];
                *(f32x4*)&fv[0] = *(const f32x4*)(sp);
                *(f32x4*)&fv[4] = *(const f32x4*)(sp + 4);
                fB[nt][k0] = pack8(fv);
            }
        }
    }
    const float bhn0 = bhh[512 + 32 * wid + (lane & 15)];
    const float bhn1 = bhh[512 + 32 * wid + 16 + (lane & 15)];

    for (int i = tid; i < 16 * HB / 2; i += 512) ((uint32_t*)hb)[i] = 0;
    __syncthreads();

    const unsigned short* XTw = XT + (size_t)bid * T_ * XT_STRIDE;
    s16x8 XA[3], XB[3];
    {   // prologue: load xT(t(0))
        const int t0 = dir ? (T_ - 1) : 0;
        const s16x8* p = (const s16x8*)(XTw + (size_t)t0 * XT_STRIDE) + (size_t)tid * 3;
        XA[0] = p[0]; XA[1] = p[1]; XA[2] = p[2];
    }
#pragma unroll 1
    for (int s = 0; s < T_; s += 2) {
        gru_step<0>(s,     dir, b0, tid, lane, wid, XTw, out, hb, fB, bhn0, bhn1, XA, XB);
        gru_step<1>(s + 1, dir, b0, tid, lane, wid, XTw, out, hb, fB, bhn0, bhn1, XB, XA);
    }
}

extern "C" void kernel_launch(void* const* d_in, const int* in_sizes, int n_in,
                              void* d_out, int out_size, void* d_ws, size_t ws_size,
                              hipStream_t stream) {
    const float* x     = (const float*)d_in[0];
    const float* wih_f = (const float*)d_in[1];
    const float* whh_f = (const float*)d_in[2];
    const float* bih_f = (const float*)d_in[3];
    const float* bhh_f = (const float*)d_in[4];
    const float* wih_b = (const float*)d_in[5];
    const float* whh_b = (const float*)d_in[6];
    const float* bih_b = (const float*)d_in[7];
    const float* bhh_b = (const float*)d_in[8];
    float* out = (float*)d_out;

    unsigned short* wbf = (unsigned short*)d_ws;
    unsigned short* XT  = (unsigned short*)((char*)d_ws + 786432);

    k_convert<<<dim3(768), dim3(512), 0, stream>>>(wih_f, wih_b, wbf);
    k_xgemm<<<dim3(512, 8), dim3(512), 0, stream>>>(x, wbf, bih_f, bhh_f, bih_b, bhh_b, XT);
    k_recur<<<dim3(16), dim3(512), 0, stream>>>(whh_f, whh_b, bhh_f, bhh_b, XT, out);
}